// Round 6
// baseline (2796.979 us; speedup 1.0000x reference)
//
#include <hip/hip_runtime.h>
#include <hip/hip_bf16.h>
#include <stdint.h>

typedef __bf16 bf16x8 __attribute__((ext_vector_type(8)));
typedef float f32x4 __attribute__((ext_vector_type(4)));
typedef unsigned short us8 __attribute__((ext_vector_type(8)));

__device__ __forceinline__ float bf2f(unsigned short u) {
    return __uint_as_float(((unsigned)u) << 16);
}
__device__ __forceinline__ unsigned short f2bf(float f) {
    __bf16 b = (__bf16)f;  // RNE
    return __builtin_bit_cast(unsigned short, b);
}

__device__ __forceinline__ void gload16(const char* g, char* l) {
    __builtin_amdgcn_global_load_lds(
        (const __attribute__((address_space(1))) void*)g,
        (__attribute__((address_space(3))) void*)l, 16, 0, 0);
}

// ---------------------------------------------------------------------------
// Transpose + cast: in (K x N) f32  ->  out (N x K) bf16
// ---------------------------------------------------------------------------
__global__ __launch_bounds__(256) void transpose_cast(
    const float* __restrict__ in, unsigned short* __restrict__ out,
    int K, int N)
{
    __shared__ float tile[32][33];
    const int tx = threadIdx.x, ty = threadIdx.y;  // (32, 8)
    const int n0 = blockIdx.x * 32, k0 = blockIdx.y * 32;
    #pragma unroll
    for (int i = 0; i < 32; i += 8)
        tile[ty + i][tx] = in[(long)(k0 + ty + i) * N + n0 + tx];
    __syncthreads();
    #pragma unroll
    for (int i = 0; i < 32; i += 8)
        out[(long)(n0 + ty + i) * K + k0 + tx] = f2bf(tile[tx][ty + i]);
}

// ---------------------------------------------------------------------------
// Elementwise cast f32 -> bf16 (vectorized, grid-stride)
// ---------------------------------------------------------------------------
__global__ __launch_bounds__(256) void cast_f32_bf16(
    const float* __restrict__ in, unsigned short* __restrict__ out, long n)
{
    const long stride = (long)gridDim.x * 256 * 8;
    for (long i = ((long)blockIdx.x * 256 + threadIdx.x) * 8; i < n; i += stride) {
        const f32x4 u0 = *(const f32x4*)&in[i];
        const f32x4 u1 = *(const f32x4*)&in[i + 4];
        us8 w;
        #pragma unroll
        for (int e = 0; e < 4; ++e) { w[e] = f2bf(u0[e]); w[e + 4] = f2bf(u1[e]); }
        *(us8*)&out[i] = w;
    }
}

// ---------------------------------------------------------------------------
// GEMM: C(M,N) = A(M,K) @ BT(N,K)^T + bias(N)       (A, BT bf16; K % 128 == 0)
// 256x256 tile, BK=64, 512 threads (8 waves, 2M x 4N), 128KB dbuf LDS.
// Overlapped 4-phase K-loop: each phase = {BAR; issue NEXT quadrant's
// ds_reads; MFMA CURRENT quadrant (operands read last phase); stage gloads}.
// LDS unit services reads UNDER the MFMA burst (pipe overlap).  One barrier
// per phase.  Counted vmcnt(4) at P1-end BEFORE the P2 barrier (drain own
// t+1 stages, barrier publishes cross-wave).  Never vmcnt(0) until tail.
// ---------------------------------------------------------------------------
#define MFMA16x16(a, b, c) __builtin_amdgcn_mfma_f32_16x16x32_bf16(a, b, c, 0, 0, 0)
#define BAR __builtin_amdgcn_s_barrier()

#define MFMA_Q(AA, BB, RO, CO)                                                 \
    _Pragma("unroll") for (int mi_ = 0; mi_ < 4; ++mi_)                        \
        _Pragma("unroll") for (int ni_ = 0; ni_ < 2; ++ni_) {                  \
            acc[(RO)+mi_][(CO)+ni_] =                                          \
                MFMA16x16(AA[mi_][0], BB[ni_][0], acc[(RO)+mi_][(CO)+ni_]);    \
            acc[(RO)+mi_][(CO)+ni_] =                                          \
                MFMA16x16(AA[mi_][1], BB[ni_][1], acc[(RO)+mi_][(CO)+ni_]);    \
        }

// Region death/staging schedule (issue-order + barriers + latency):
//   ALOc read pre-P0  -> A j0,j2 regions staged at P0-end
//   AHI  read in P0   -> A j1,j3 regions staged at P1-end
//   BLOc read in prev P2, BHI in P1 -> B regions staged at P2-end
//   OBUF reads (BLOn@P2, ALOn@P3) guarded by vmcnt@P1-end + P2 barrier.
#define TILE_BODY(T, BUF, OBUF, ALOc, BLOc, ALOn, BLOn)                        \
  do {                                                                         \
    const bool sG = ((T) + 2 < KT);                                            \
    const bool sR = ((T) + 1 < KT);                                            \
    const long gk = (long)((T) + 2) * 128;                                     \
    /* ---- P0: reads AHI(BUF) under MFMA Q0 = ALOc x BLOc; stage A j0,j2 */   \
    BAR;                                                                       \
    _Pragma("unroll") for (int mi = 0; mi < 4; ++mi) {                         \
        AHI[mi][0] = *(const bf16x8*)(smem + (BUF) + aBase + 8192 + mi*2048 + k0); \
        AHI[mi][1] = *(const bf16x8*)(smem + (BUF) + aBase + 8192 + mi*2048 + k1); \
    }                                                                          \
    __builtin_amdgcn_s_setprio(1);                                             \
    MFMA_Q(ALOc, BLOc, 0, 0)                                                   \
    __builtin_amdgcn_s_setprio(0);                                             \
    if (sG) {                                                                  \
        gload16(aStage + (long)(0*64)*Kb + gk, smem + (BUF) + 0*8192 + ldsW);  \
        gload16(aStage + (long)(2*64)*Kb + gk, smem + (BUF) + 2*8192 + ldsW);  \
    }                                                                          \
    /* ---- P1: reads BHI(BUF) under MFMA Q1 = AHI x BLOc; stage A j1,j3;      \
       counted vmcnt BEFORE the P2 barrier (publishes t+1 stages) ---- */      \
    BAR;                                                                       \
    _Pragma("unroll") for (int nj = 0; nj < 2; ++nj) {                         \
        BHI[nj][0] = *(const bf16x8*)(smem + (BUF) + bBase + (2+nj)*2048 + k0); \
        BHI[nj][1] = *(const bf16x8*)(smem + (BUF) + bBase + (2+nj)*2048 + k1); \
    }                                                                          \
    __builtin_amdgcn_s_setprio(1);                                             \
    MFMA_Q(AHI, BLOc, 4, 0)                                                    \
    __builtin_amdgcn_s_setprio(0);                                             \
    if (sG) {                                                                  \
        gload16(aStage + (long)(1*64)*Kb + gk, smem + (BUF) + 1*8192 + ldsW);  \
        gload16(aStage + (long)(3*64)*Kb + gk, smem + (BUF) + 3*8192 + ldsW);  \
    }                                                                          \
    if (sR) {                                                                  \
        if (sG) asm volatile("s_waitcnt vmcnt(4)");  /* drain t+1, keep t+2 */ \
        else    asm volatile("s_waitcnt vmcnt(0)");  /* tail */                \
    }                                                                          \
    /* ---- P2: reads BLOn(OBUF) under MFMA Q2 = ALOc x BHI; stage B j0..3 */  \
    BAR;                                                                       \
    if (sR) {                                                                  \
        _Pragma("unroll") for (int ni = 0; ni < 2; ++ni) {                     \
            BLOn[ni][0] = *(const bf16x8*)(smem + (OBUF) + bBase + ni*2048 + k0); \
            BLOn[ni][1] = *(const bf16x8*)(smem + (OBUF) + bBase + ni*2048 + k1); \
        }                                                                      \
    }                                                                          \
    __builtin_amdgcn_s_setprio(1);                                             \
    MFMA_Q(ALOc, BHI, 0, 2)                                                    \
    __builtin_amdgcn_s_setprio(0);                                             \
    if (sG) {                                                                  \
        _Pragma("unroll") for (int j = 0; j < 4; ++j)                          \
            gload16(bStage + (long)(j*64)*Kb + gk,                             \
                    smem + (BUF) + 32768 + j*8192 + ldsW);                     \
    }                                                                          \
    /* ---- P3: reads ALOn(OBUF) under MFMA Q3 = AHI x BHI ---- */             \
    BAR;                                                                       \
    if (sR) {                                                                  \
        _Pragma("unroll") for (int mi = 0; mi < 4; ++mi) {                     \
            ALOn[mi][0] = *(const bf16x8*)(smem + (OBUF) + aBase + mi*2048 + k0); \
            ALOn[mi][1] = *(const bf16x8*)(smem + (OBUF) + aBase + mi*2048 + k1); \
        }                                                                      \
    }                                                                          \
    __builtin_amdgcn_s_setprio(1);                                             \
    MFMA_Q(AHI, BHI, 4, 2)                                                     \
    __builtin_amdgcn_s_setprio(0);                                             \
  } while (0)

template<bool OUT_BF16>
__global__ __launch_bounds__(512, 2)
void gemm256(const unsigned short* __restrict__ A,   // M x K bf16
             const unsigned short* __restrict__ BT,  // N x K bf16
             const float* __restrict__ bias,
             void* __restrict__ Cp,
             int M, int N, int K)
{
    extern __shared__ char smem[];   // 131072: 2 bufs x (A 32K | B 32K)
    const int tid  = threadIdx.x;
    const int lane = tid & 63;
    const int w    = tid >> 6;      // wave 0..7
    const int wm   = w >> 2;        // 0..1 (M split)
    const int wn   = w & 3;         // 0..3 (N split)

    // XCD-bijective swizzle (launcher guarantees gridDim.x % 8 == 0)
    const int nwg  = gridDim.x;
    const int bid0 = blockIdx.x;
    const int bid  = (bid0 & 7) * (nwg >> 3) + (bid0 >> 3);
    const int nbx  = N >> 8;
    const int bx   = bid % nbx, by = bid / nbx;
    const long rowStart = (long)by * 256;
    const int  colStart = bx * 256;

    const int  KT = K >> 6;          // 16
    const long Kb = (long)K * 2;     // row stride bytes

    // staging: instr (mat, j) covers tile rows j*64 + w*8 + (lane>>3)
    const int srow = w * 8 + (lane >> 3);
    const int scol = ((lane & 7) ^ (lane >> 3)) << 4;   // inverse-swizzled src col
    const char* aStage = (const char*)A  + (rowStart + srow) * Kb + scol;
    const char* bStage = (const char*)BT + ((long)colStart + srow) * Kb + scol;
    const int ldsW = w * 1024;

    // fragment-read offsets (swizzled)
    const int fr = lane & 15;
    const int kq = lane >> 4;                      // 0..3
    const int sw = (fr & 7) << 4;
    const int k0 = (kq * 16) ^ sw;
    const int k1 = (64 + kq * 16) ^ sw;
    const int aBase = (wm * 128 + fr) * 128;           // bytes, A region
    const int bBase = 32768 + (wn * 64 + fr) * 128;    // bytes, B region

    f32x4 acc[8][4] = {};
    bf16x8 ALO0[4][2], BLO0[2][2], ALO1[4][2], BLO1[2][2], AHI[4][2], BHI[2][2];

    // ---- prologue: stage K-tiles 0 (buf0) and 1 (buf1) ----
    #pragma unroll
    for (int tt = 0; tt < 2; ++tt) {
        #pragma unroll
        for (int j = 0; j < 4; ++j)
            gload16(aStage + (long)(j * 64) * Kb + (long)tt * 128,
                    smem + tt * 65536 + j * 8192 + ldsW);
        #pragma unroll
        for (int j = 0; j < 4; ++j)
            gload16(bStage + (long)(j * 64) * Kb + (long)tt * 128,
                    smem + tt * 65536 + 32768 + j * 8192 + ldsW);
    }
    asm volatile("s_waitcnt vmcnt(8)");   // tile 0 landed; tile 1 in flight
    BAR;                                   // publish tile-0 stages cross-wave
    #pragma unroll
    for (int ni = 0; ni < 2; ++ni) {
        BLO0[ni][0] = *(const bf16x8*)(smem + bBase + ni*2048 + k0);
        BLO0[ni][1] = *(const bf16x8*)(smem + bBase + ni*2048 + k1);
    }
    #pragma unroll
    for (int mi = 0; mi < 4; ++mi) {
        ALO0[mi][0] = *(const bf16x8*)(smem + aBase + mi*2048 + k0);
        ALO0[mi][1] = *(const bf16x8*)(smem + aBase + mi*2048 + k1);
    }

    #pragma unroll 1
    for (int tp = 0; tp < KT / 2; ++tp) {
        TILE_BODY(2 * tp,     0,     65536, ALO0, BLO0, ALO1, BLO1);
        TILE_BODY(2 * tp + 1, 65536, 0,     ALO1, BLO1, ALO0, BLO0);
    }

    // ---- epilogue: C/D frag layout col=lane&15, row=(lane>>4)*4+e ----
    float bv[4];
    #pragma unroll
    for (int ni = 0; ni < 4; ++ni)
        bv[ni] = bias[colStart + wn * 64 + ni * 16 + fr];
    #pragma unroll
    for (int mi = 0; mi < 8; ++mi) {
        #pragma unroll
        for (int ni = 0; ni < 4; ++ni) {
            const int col = colStart + wn * 64 + ni * 16 + fr;
            #pragma unroll
            for (int e = 0; e < 4; ++e) {
                const long row = rowStart + wm * 128 + mi * 16 + kq * 4 + e;
                const float val = acc[mi][ni][e] + bv[ni];
                if constexpr (OUT_BF16)
                    ((unsigned short*)Cp)[row * N + col] = f2bf(val);
                else
                    ((float*)Cp)[row * N + col] = val;
            }
        }
    }
}

// ---------------------------------------------------------------------------
// Per-token head-mixing attention (unchanged, verified).
// ---------------------------------------------------------------------------
__global__ __launch_bounds__(256) void attn_kernel(
    const unsigned short* __restrict__ qkv, unsigned short* __restrict__ out)
{
    __shared__ unsigned short qkvs[4][3072];
    __shared__ float ps[4][256];
    __shared__ unsigned short os[4][1024];
    const int tid = threadIdx.x, lane = tid & 63, wave = tid >> 6;
    const long blockTok = (long)blockIdx.x * 4;

    const unsigned short* src = qkv + blockTok * 3072;
    unsigned short* dstBase = &qkvs[0][0];
    #pragma unroll
    for (int i = 0; i < 6; ++i) {
        const int o = (i * 256 + tid) * 8;
        *(us8*)&dstBase[o] = *(const us8*)&src[o];
    }
    __syncthreads();

    const unsigned short* q = &qkvs[wave][0];
    const unsigned short* kk = &qkvs[wave][1024];
    const unsigned short* vv = &qkvs[wave][2048];
    const int h = lane >> 2, g4 = lane & 3;

    float s[4] = {0.f, 0.f, 0.f, 0.f};
    #pragma unroll
    for (int d0 = 0; d0 < 64; d0 += 8) {
        const us8 q8 = *(const us8*)&q[h * 64 + d0];
        float qf[8];
        #pragma unroll
        for (int e = 0; e < 8; ++e) qf[e] = bf2f(q8[e]);
        #pragma unroll
        for (int j = 0; j < 4; ++j) {
            const us8 k8 = *(const us8*)&kk[(g4 * 4 + j) * 64 + d0];
            #pragma unroll
            for (int e = 0; e < 8; ++e) s[j] += qf[e] * bf2f(k8[e]);
        }
    }
    #pragma unroll
    for (int j = 0; j < 4; ++j) s[j] *= 0.125f;

    float mx = fmaxf(fmaxf(s[0], s[1]), fmaxf(s[2], s[3]));
    mx = fmaxf(mx, __shfl_xor(mx, 1, 64));
    mx = fmaxf(mx, __shfl_xor(mx, 2, 64));
    float p[4], sum = 0.f;
    #pragma unroll
    for (int j = 0; j < 4; ++j) { p[j] = expf(s[j] - mx); sum += p[j]; }
    sum += __shfl_xor(sum, 1, 64);
    sum += __shfl_xor(sum, 2, 64);
    const float inv = 1.f / sum;
    #pragma unroll
    for (int j = 0; j < 4; ++j) ps[wave][h * 16 + g4 * 4 + j] = p[j] * inv;
    __syncthreads();

    const int db = lane & 3;
    float o16[16] = {};
    #pragma unroll
    for (int gq = 0; gq < 4; ++gq) {
        const f32x4 pv = *(const f32x4*)&ps[wave][h * 16 + gq * 4];
        #pragma unroll
        for (int j = 0; j < 4; ++j) {
            const float pg = pv[j];
            const int g = gq * 4 + j;
            const us8 v8a = *(const us8*)&vv[g * 64 + db * 16];
            const us8 v8b = *(const us8*)&vv[g * 64 + db * 16 + 8];
            #pragma unroll
            for (int e = 0; e < 8; ++e) {
                o16[e]     += pg * bf2f(v8a[e]);
                o16[8 + e] += pg * bf2f(v8b[e]);
            }
        }
    }
    us8 w0, w1;
    #pragma unroll
    for (int e = 0; e < 8; ++e) { w0[e] = f2bf(o16[e]); w1[e] = f2bf(o16[8 + e]); }
    *(us8*)&os[wave][h * 64 + db * 16] = w0;
    *(us8*)&os[wave][h * 64 + db * 16 + 8] = w1;
    __syncthreads();

    #pragma unroll
    for (int i = 0; i < 2; ++i) {
        const int c = i * 256 + tid;
        const int w2 = c >> 7;
        const int cc = c & 127;
        const long m = blockTok + w2;
        const long n_ = m >> 12;
        const int t = (int)(m & 4095);
        const int hh = cc >> 3, slot = cc & 7;
        const long row = n_ * 4096 + hh * 256 + (t >> 4);
        const long colb = (long)(t & 15) * 128 + slot * 16;
        *(us8*)((char*)out + row * 2048 + colb) = *(const us8*)&os[w2][cc * 8];
    }
}

// ---------------------------------------------------------------------------
extern "C" void kernel_launch(void* const* d_in, const int* in_sizes, int n_in,
                              void* d_out, int out_size, void* d_ws, size_t ws_size,
                              hipStream_t stream) {
    const float* x      = (const float*)d_in[0];  // (16,4096,1024)
    const float* w_qkv  = (const float*)d_in[1];  // (1024,3072)
    const float* b_qkv  = (const float*)d_in[2];  // (3072)
    const float* w_proj = (const float*)d_in[3];  // (1024,1024)
    const float* b_proj = (const float*)d_in[4];  // (1024)

    const long M = 65536;  // 16*4096 tokens
    const size_t QKV_B = (size_t)M * 3072 * 2;    // 402,653,184
    const size_t XB_B  = (size_t)M * 1024 * 2;    // 134,217,728 (x-bf16, then attnout)
    const size_t WQ_B  = 3072 * 1024 * 2;
    const size_t WP_B  = 1024 * 1024 * 2;
    if (ws_size < QKV_B + XB_B + WQ_B + WP_B) return;  // ~545MB

    char* ws = (char*)d_ws;
    unsigned short* qkv    = (unsigned short*)ws;
    unsigned short* xb     = (unsigned short*)(ws + QKV_B);          // also attnout
    unsigned short* wqkvT  = (unsigned short*)(ws + QKV_B + XB_B);
    unsigned short* wprojT = (unsigned short*)(ws + QKV_B + XB_B + WQ_B);

    hipFuncSetAttribute((const void*)gemm256<true>,
                        hipFuncAttributeMaxDynamicSharedMemorySize, 131072);
    hipFuncSetAttribute((const void*)gemm256<false>,
                        hipFuncAttributeMaxDynamicSharedMemorySize, 131072);

    dim3 tb(32, 8);
    transpose_cast<<<dim3(3072 / 32, 1024 / 32), tb, 0, stream>>>(w_qkv, wqkvT, 1024, 3072);
    transpose_cast<<<dim3(1024 / 32, 1024 / 32), tb, 0, stream>>>(w_proj, wprojT, 1024, 1024);
    cast_f32_bf16<<<2048, 256, 0, stream>>>(x, xb, M * 1024);

    // qkv = x @ w_qkv + b_qkv   (bf16 out); grid 12*256=3072 (%8==0)
    gemm256<true><<<dim3((3072 / 256) * (M / 256)), 512, 131072, stream>>>(
        xb, wqkvT, b_qkv, qkv, (int)M, 3072, 1024);

    // per-token attention -> scrambled attnout (bf16), reusing xb
    attn_kernel<<<dim3(M / 4), 256, 0, stream>>>(qkv, xb);

    // out = attnout @ w_proj + b_proj   (f32 out); grid 4*256=1024 (%8==0)
    gemm256<false><<<dim3((1024 / 256) * (M / 256)), 512, 131072, stream>>>(
        xb, wprojT, b_proj, d_out, (int)M, 1024, 1024);
}

// Round 7
// 762.954 us; speedup vs baseline: 3.6660x; 3.6660x over previous
//
#include <hip/hip_runtime.h>
#include <hip/hip_bf16.h>
#include <stdint.h>

typedef __bf16 bf16x8 __attribute__((ext_vector_type(8)));
typedef float f32x4 __attribute__((ext_vector_type(4)));
typedef unsigned short us8 __attribute__((ext_vector_type(8)));

__device__ __forceinline__ float bf2f(unsigned short u) {
    return __uint_as_float(((unsigned)u) << 16);
}
__device__ __forceinline__ unsigned short f2bf(float f) {
    __bf16 b = (__bf16)f;  // RNE
    return __builtin_bit_cast(unsigned short, b);
}

__device__ __forceinline__ void gload16(const char* g, char* l) {
    __builtin_amdgcn_global_load_lds(
        (const __attribute__((address_space(1))) void*)g,
        (__attribute__((address_space(3))) void*)l, 16, 0, 0);
}

// ---------------------------------------------------------------------------
// Transpose + cast: in (K x N) f32  ->  out (N x K) bf16
// ---------------------------------------------------------------------------
__global__ __launch_bounds__(256) void transpose_cast(
    const float* __restrict__ in, unsigned short* __restrict__ out,
    int K, int N)
{
    __shared__ float tile[32][33];
    const int tx = threadIdx.x, ty = threadIdx.y;  // (32, 8)
    const int n0 = blockIdx.x * 32, k0 = blockIdx.y * 32;
    #pragma unroll
    for (int i = 0; i < 32; i += 8)
        tile[ty + i][tx] = in[(long)(k0 + ty + i) * N + n0 + tx];
    __syncthreads();
    #pragma unroll
    for (int i = 0; i < 32; i += 8)
        out[(long)(n0 + ty + i) * K + k0 + tx] = f2bf(tile[tx][ty + i]);
}

// ---------------------------------------------------------------------------
// Elementwise cast f32 -> bf16 (vectorized, grid-stride)
// ---------------------------------------------------------------------------
__global__ __launch_bounds__(256) void cast_f32_bf16(
    const float* __restrict__ in, unsigned short* __restrict__ out, long n)
{
    const long stride = (long)gridDim.x * 256 * 8;
    for (long i = ((long)blockIdx.x * 256 + threadIdx.x) * 8; i < n; i += stride) {
        const f32x4 u0 = *(const f32x4*)&in[i];
        const f32x4 u1 = *(const f32x4*)&in[i + 4];
        us8 w;
        #pragma unroll
        for (int e = 0; e < 4; ++e) { w[e] = f2bf(u0[e]); w[e + 4] = f2bf(u1[e]); }
        *(us8*)&out[i] = w;
    }
}

// ---------------------------------------------------------------------------
// GEMM: C(M,N) = A(M,K) @ BT(N,K)^T + bias(N)       (A, BT bf16; K == 1024)
// 256x256 tile, BK=64, 512 threads (8 waves, 2M x 4N), 128KB dbuf LDS.
// 8-phase read-ahead K-loop: phase p issues the NEXT quadrant's ds_reads
// (pinned above the MFMA burst by sched_barrier pair), then a COUNTED
// lgkmcnt(R_p) (drains the previous phase's reads, keeps this phase's in
// flight under the MFMA burst).  8 MFMA per phase.  Region-death staging
// (A j0,j2 @S3; A j1,j3 @S5; B @S6,S7); vmcnt(4) at S5-end before S6's
// barrier.  Tail tiles peeled with compile-time flags.  Peak frag liveness
// ~16 x b128 = 64 VGPR (+128 acc) -> fits 256-reg budget, no spills.
// ---------------------------------------------------------------------------
#define MFMA16x16(a, b, c) __builtin_amdgcn_mfma_f32_16x16x32_bf16(a, b, c, 0, 0, 0)
#define BAR __builtin_amdgcn_s_barrier()
#define SB  __builtin_amdgcn_sched_barrier(0)
#define P1_ __builtin_amdgcn_s_setprio(1);
#define P0_ __builtin_amdgcn_s_setprio(0);

#define MFMA_H(AA, BB, RO, CO)                                                 \
    _Pragma("unroll") for (int mi_ = 0; mi_ < 4; ++mi_)                        \
        _Pragma("unroll") for (int ni_ = 0; ni_ < 2; ++ni_)                    \
            acc[(RO)+mi_][(CO)+ni_] =                                          \
                MFMA16x16(AA[mi_], BB[ni_], acc[(RO)+mi_][(CO)+ni_]);

#define RD_A(DST, BUFOFF, HIOFF, KS)                                           \
    _Pragma("unroll") for (int mi_ = 0; mi_ < 4; ++mi_)                        \
        DST[mi_] = *(const bf16x8*)(smem + (BUFOFF) + aBase + (HIOFF) + mi_*2048 + (KS));

#define RD_B(DST, BUFOFF, NOFF, KS)                                            \
    _Pragma("unroll") for (int ni_ = 0; ni_ < 2; ++ni_)                        \
        DST[ni_] = *(const bf16x8*)(smem + (BUFOFF) + bBase + ((NOFF)+ni_)*2048 + (KS));

// One K-tile = 8 phases S0..S7.  SG/SR are LITERAL 0/1 (folded).
#define TILE8(T_, BUF, OBUF, SG, SR)                                           \
  do {                                                                         \
    const long gk = (long)((T_) + 2) * 128;                                    \
    /* S0: rd AH0; mfma AL0xBL0 */                                             \
    BAR; RD_A(AH0, BUF, 8192, k0)                                              \
    SB; asm volatile("s_waitcnt lgkmcnt(4)"); SB;                              \
    P1_ MFMA_H(AL0, BL0, 0, 0) P0_                                             \
    /* S1: rd BH0; mfma AH0xBL0 */                                             \
    BAR; RD_B(BH0, BUF, 2, k0)                                                 \
    SB; asm volatile("s_waitcnt lgkmcnt(2)"); SB;                              \
    P1_ MFMA_H(AH0, BL0, 4, 0) P0_                                             \
    /* S2: rd AL1; mfma AH0xBH0 */                                             \
    BAR; RD_A(AL1, BUF, 0, k1)                                                 \
    SB; asm volatile("s_waitcnt lgkmcnt(4)"); SB;                              \
    P1_ MFMA_H(AH0, BH0, 4, 2) P0_                                             \
    /* S3: rd BL1; stage A j0,j2; mfma AL0xBH0 */                              \
    BAR; RD_B(BL1, BUF, 0, k1)                                                 \
    if (SG) {                                                                  \
        gload16(aStage + (long)(0*64)*Kb + gk, smem + (BUF) + 0*8192 + ldsW);  \
        gload16(aStage + (long)(2*64)*Kb + gk, smem + (BUF) + 2*8192 + ldsW);  \
    }                                                                          \
    SB; asm volatile("s_waitcnt lgkmcnt(2)"); SB;                              \
    P1_ MFMA_H(AL0, BH0, 0, 2) P0_                                             \
    /* S4: rd AH1; mfma AL1xBL1 */                                             \
    BAR; RD_A(AH1, BUF, 8192, k1)                                              \
    SB; asm volatile("s_waitcnt lgkmcnt(4)"); SB;                              \
    P1_ MFMA_H(AL1, BL1, 0, 0) P0_                                             \
    /* S5: rd BH1; stage A j1,j3; mfma AH1xBL1; counted vmcnt */               \
    BAR; RD_B(BH1, BUF, 2, k1)                                                 \
    if (SG) {                                                                  \
        gload16(aStage + (long)(1*64)*Kb + gk, smem + (BUF) + 1*8192 + ldsW);  \
        gload16(aStage + (long)(3*64)*Kb + gk, smem + (BUF) + 3*8192 + ldsW);  \
    }                                                                          \
    SB; asm volatile("s_waitcnt lgkmcnt(2)"); SB;                              \
    P1_ MFMA_H(AH1, BL1, 4, 0) P0_                                             \
    SB;                                                                        \
    if (SG) asm volatile("s_waitcnt vmcnt(4)");                                \
    else    asm volatile("s_waitcnt vmcnt(0)");                                \
    SB;                                                                        \
    /* S6: rd BL0'(OBUF); stage B j0,j1; mfma AH1xBH1 */                       \
    BAR;                                                                       \
    if (SR) { RD_B(BL0, OBUF, 0, k0) }                                         \
    if (SG) {                                                                  \
        gload16(bStage + (long)(0*64)*Kb + gk, smem + (BUF) + 32768 + 0*8192 + ldsW); \
        gload16(bStage + (long)(1*64)*Kb + gk, smem + (BUF) + 32768 + 1*8192 + ldsW); \
    }                                                                          \
    SB;                                                                        \
    if (SR) asm volatile("s_waitcnt lgkmcnt(2)");                              \
    else    asm volatile("s_waitcnt lgkmcnt(0)");                              \
    SB;                                                                        \
    P1_ MFMA_H(AH1, BH1, 4, 2) P0_                                             \
    /* S7: rd AL0'(OBUF); stage B j2,j3; mfma AL1xBH1 */                       \
    BAR;                                                                       \
    if (SR) { RD_A(AL0, OBUF, 0, k0) }                                         \
    if (SG) {                                                                  \
        gload16(bStage + (long)(2*64)*Kb + gk, smem + (BUF) + 32768 + 2*8192 + ldsW); \
        gload16(bStage + (long)(3*64)*Kb + gk, smem + (BUF) + 32768 + 3*8192 + ldsW); \
    }                                                                          \
    SB;                                                                        \
    if (SR) asm volatile("s_waitcnt lgkmcnt(4)");                              \
    else    asm volatile("s_waitcnt lgkmcnt(0)");                              \
    SB;                                                                        \
    P1_ MFMA_H(AL1, BH1, 0, 2) P0_                                             \
  } while (0)

template<bool OUT_BF16>
__global__ __launch_bounds__(512, 2)
void gemm256(const unsigned short* __restrict__ A,   // M x K bf16
             const unsigned short* __restrict__ BT,  // N x K bf16
             const float* __restrict__ bias,
             void* __restrict__ Cp,
             int M, int N, int K)
{
    extern __shared__ char smem[];   // 131072: 2 bufs x (A 32K | B 32K)
    const int tid  = threadIdx.x;
    const int lane = tid & 63;
    const int w    = tid >> 6;      // wave 0..7
    const int wm   = w >> 2;        // 0..1 (M split)
    const int wn   = w & 3;         // 0..3 (N split)

    // XCD-bijective swizzle (launcher guarantees gridDim.x % 8 == 0)
    const int nwg  = gridDim.x;
    const int bid0 = blockIdx.x;
    const int bid  = (bid0 & 7) * (nwg >> 3) + (bid0 >> 3);
    const int nbx  = N >> 8;
    const int bx   = bid % nbx, by = bid / nbx;
    const long rowStart = (long)by * 256;
    const int  colStart = bx * 256;

    const long Kb = (long)K * 2;     // row stride bytes (K == 1024, KT == 16)

    // staging: instr (mat, j) covers tile rows j*64 + w*8 + (lane>>3)
    const int srow = w * 8 + (lane >> 3);
    const int scol = ((lane & 7) ^ (lane >> 3)) << 4;   // inverse-swizzled src col
    const char* aStage = (const char*)A  + (rowStart + srow) * Kb + scol;
    const char* bStage = (const char*)BT + ((long)colStart + srow) * Kb + scol;
    const int ldsW = w * 1024;

    // fragment-read offsets (swizzled)
    const int fr = lane & 15;
    const int kq = lane >> 4;                      // 0..3
    const int sw = (fr & 7) << 4;
    const int k0 = (kq * 16) ^ sw;
    const int k1 = (64 + kq * 16) ^ sw;
    const int aBase = (wm * 128 + fr) * 128;           // bytes, A region
    const int bBase = 32768 + (wn * 64 + fr) * 128;    // bytes, B region

    f32x4 acc[8][4] = {};
    bf16x8 AL0[4], AH0[4], AL1[4], AH1[4], BL0[2], BH0[2], BL1[2], BH1[2];

    // ---- prologue: stage K-tiles 0 (buf0) and 1 (buf1) ----
    #pragma unroll
    for (int tt = 0; tt < 2; ++tt) {
        #pragma unroll
        for (int j = 0; j < 4; ++j)
            gload16(aStage + (long)(j * 64) * Kb + (long)tt * 128,
                    smem + tt * 65536 + j * 8192 + ldsW);
        #pragma unroll
        for (int j = 0; j < 4; ++j)
            gload16(bStage + (long)(j * 64) * Kb + (long)tt * 128,
                    smem + tt * 65536 + 32768 + j * 8192 + ldsW);
    }
    asm volatile("s_waitcnt vmcnt(8)");   // tile 0 landed; tile 1 in flight
    BAR;                                   // publish tile-0 stages
    RD_B(BL0, 0, 0, k0)                    // preload S0 operands (6 reads)
    RD_A(AL0, 0, 0, k0)
    // S0's lgkmcnt(4) (after its 4 AH0 reads) drains these 6.

    #pragma unroll 1
    for (int tp = 0; tp < 7; ++tp) {       // tiles 0..13, full pipeline
        TILE8(2 * tp,     0,     65536, 1, 1);
        TILE8(2 * tp + 1, 65536, 0,     1, 1);
    }
    TILE8(14, 0,     65536, 0, 1);         // no staging; drain vmcnt
    TILE8(15, 65536, 0,     0, 0);         // tail: no next-tile reads

    // ---- epilogue: C/D frag layout col=lane&15, row=(lane>>4)*4+e ----
    float bv[4];
    #pragma unroll
    for (int ni = 0; ni < 4; ++ni)
        bv[ni] = bias[colStart + wn * 64 + ni * 16 + fr];
    #pragma unroll
    for (int mi = 0; mi < 8; ++mi) {
        #pragma unroll
        for (int ni = 0; ni < 4; ++ni) {
            const int col = colStart + wn * 64 + ni * 16 + fr;
            #pragma unroll
            for (int e = 0; e < 4; ++e) {
                const long row = rowStart + wm * 128 + mi * 16 + kq * 4 + e;
                const float val = acc[mi][ni][e] + bv[ni];
                if constexpr (OUT_BF16)
                    ((unsigned short*)Cp)[row * N + col] = f2bf(val);
                else
                    ((float*)Cp)[row * N + col] = val;
            }
        }
    }
}

// ---------------------------------------------------------------------------
// Per-token head-mixing attention (unchanged, verified).
// ---------------------------------------------------------------------------
__global__ __launch_bounds__(256) void attn_kernel(
    const unsigned short* __restrict__ qkv, unsigned short* __restrict__ out)
{
    __shared__ unsigned short qkvs[4][3072];
    __shared__ float ps[4][256];
    __shared__ unsigned short os[4][1024];
    const int tid = threadIdx.x, lane = tid & 63, wave = tid >> 6;
    const long blockTok = (long)blockIdx.x * 4;

    const unsigned short* src = qkv + blockTok * 3072;
    unsigned short* dstBase = &qkvs[0][0];
    #pragma unroll
    for (int i = 0; i < 6; ++i) {
        const int o = (i * 256 + tid) * 8;
        *(us8*)&dstBase[o] = *(const us8*)&src[o];
    }
    __syncthreads();

    const unsigned short* q = &qkvs[wave][0];
    const unsigned short* kk = &qkvs[wave][1024];
    const unsigned short* vv = &qkvs[wave][2048];
    const int h = lane >> 2, g4 = lane & 3;

    float s[4] = {0.f, 0.f, 0.f, 0.f};
    #pragma unroll
    for (int d0 = 0; d0 < 64; d0 += 8) {
        const us8 q8 = *(const us8*)&q[h * 64 + d0];
        float qf[8];
        #pragma unroll
        for (int e = 0; e < 8; ++e) qf[e] = bf2f(q8[e]);
        #pragma unroll
        for (int j = 0; j < 4; ++j) {
            const us8 k8 = *(const us8*)&kk[(g4 * 4 + j) * 64 + d0];
            #pragma unroll
            for (int e = 0; e < 8; ++e) s[j] += qf[e] * bf2f(k8[e]);
        }
    }
    #pragma unroll
    for (int j = 0; j < 4; ++j) s[j] *= 0.125f;

    float mx = fmaxf(fmaxf(s[0], s[1]), fmaxf(s[2], s[3]));
    mx = fmaxf(mx, __shfl_xor(mx, 1, 64));
    mx = fmaxf(mx, __shfl_xor(mx, 2, 64));
    float p[4], sum = 0.f;
    #pragma unroll
    for (int j = 0; j < 4; ++j) { p[j] = expf(s[j] - mx); sum += p[j]; }
    sum += __shfl_xor(sum, 1, 64);
    sum += __shfl_xor(sum, 2, 64);
    const float inv = 1.f / sum;
    #pragma unroll
    for (int j = 0; j < 4; ++j) ps[wave][h * 16 + g4 * 4 + j] = p[j] * inv;
    __syncthreads();

    const int db = lane & 3;
    float o16[16] = {};
    #pragma unroll
    for (int gq = 0; gq < 4; ++gq) {
        const f32x4 pv = *(const f32x4*)&ps[wave][h * 16 + gq * 4];
        #pragma unroll
        for (int j = 0; j < 4; ++j) {
            const float pg = pv[j];
            const int g = gq * 4 + j;
            const us8 v8a = *(const us8*)&vv[g * 64 + db * 16];
            const us8 v8b = *(const us8*)&vv[g * 64 + db * 16 + 8];
            #pragma unroll
            for (int e = 0; e < 8; ++e) {
                o16[e]     += pg * bf2f(v8a[e]);
                o16[8 + e] += pg * bf2f(v8b[e]);
            }
        }
    }
    us8 w0, w1;
    #pragma unroll
    for (int e = 0; e < 8; ++e) { w0[e] = f2bf(o16[e]); w1[e] = f2bf(o16[8 + e]); }
    *(us8*)&os[wave][h * 64 + db * 16] = w0;
    *(us8*)&os[wave][h * 64 + db * 16 + 8] = w1;
    __syncthreads();

    #pragma unroll
    for (int i = 0; i < 2; ++i) {
        const int c = i * 256 + tid;
        const int w2 = c >> 7;
        const int cc = c & 127;
        const long m = blockTok + w2;
        const long n_ = m >> 12;
        const int t = (int)(m & 4095);
        const int hh = cc >> 3, slot = cc & 7;
        const long row = n_ * 4096 + hh * 256 + (t >> 4);
        const long colb = (long)(t & 15) * 128 + slot * 16;
        *(us8*)((char*)out + row * 2048 + colb) = *(const us8*)&os[w2][cc * 8];
    }
}

// ---------------------------------------------------------------------------
extern "C" void kernel_launch(void* const* d_in, const int* in_sizes, int n_in,
                              void* d_out, int out_size, void* d_ws, size_t ws_size,
                              hipStream_t stream) {
    const float* x      = (const float*)d_in[0];  // (16,4096,1024)
    const float* w_qkv  = (const float*)d_in[1];  // (1024,3072)
    const float* b_qkv  = (const float*)d_in[2];  // (3072)
    const float* w_proj = (const float*)d_in[3];  // (1024,1024)
    const float* b_proj = (const float*)d_in[4];  // (1024)

    const long M = 65536;  // 16*4096 tokens
    const size_t QKV_B = (size_t)M * 3072 * 2;    // 402,653,184
    const size_t XB_B  = (size_t)M * 1024 * 2;    // 134,217,728 (x-bf16, then attnout)
    const size_t WQ_B  = 3072 * 1024 * 2;
    const size_t WP_B  = 1024 * 1024 * 2;
    if (ws_size < QKV_B + XB_B + WQ_B + WP_B) return;  // ~545MB

    char* ws = (char*)d_ws;
    unsigned short* qkv    = (unsigned short*)ws;
    unsigned short* xb     = (unsigned short*)(ws + QKV_B);          // also attnout
    unsigned short* wqkvT  = (unsigned short*)(ws + QKV_B + XB_B);
    unsigned short* wprojT = (unsigned short*)(ws + QKV_B + XB_B + WQ_B);

    hipFuncSetAttribute((const void*)gemm256<true>,
                        hipFuncAttributeMaxDynamicSharedMemorySize, 131072);
    hipFuncSetAttribute((const void*)gemm256<false>,
                        hipFuncAttributeMaxDynamicSharedMemorySize, 131072);

    dim3 tb(32, 8);
    transpose_cast<<<dim3(3072 / 32, 1024 / 32), tb, 0, stream>>>(w_qkv, wqkvT, 1024, 3072);
    transpose_cast<<<dim3(1024 / 32, 1024 / 32), tb, 0, stream>>>(w_proj, wprojT, 1024, 1024);
    cast_f32_bf16<<<2048, 256, 0, stream>>>(x, xb, M * 1024);

    // qkv = x @ w_qkv + b_qkv   (bf16 out); grid 12*256=3072 (%8==0)
    gemm256<true><<<dim3((3072 / 256) * (M / 256)), 512, 131072, stream>>>(
        xb, wqkvT, b_qkv, qkv, (int)M, 3072, 1024);

    // per-token attention -> scrambled attnout (bf16), reusing xb
    attn_kernel<<<dim3(M / 4), 256, 0, stream>>>(qkv, xb);

    // out = attnout @ w_proj + b_proj   (f32 out); grid 4*256=1024 (%8==0)
    gemm256<false><<<dim3((1024 / 256) * (M / 256)), 512, 131072, stream>>>(
        xb, wprojT, b_proj, d_out, (int)M, 1024, 1024);
}

// Round 8
// 750.484 us; speedup vs baseline: 3.7269x; 1.0166x over previous
//
#include <hip/hip_runtime.h>
#include <hip/hip_bf16.h>
#include <stdint.h>

typedef __bf16 bf16x8 __attribute__((ext_vector_type(8)));
typedef float f32x4 __attribute__((ext_vector_type(4)));
typedef unsigned short us8 __attribute__((ext_vector_type(8)));

__device__ __forceinline__ float bf2f(unsigned short u) {
    return __uint_as_float(((unsigned)u) << 16);
}
__device__ __forceinline__ unsigned short f2bf(float f) {
    __bf16 b = (__bf16)f;  // RNE
    return __builtin_bit_cast(unsigned short, b);
}

__device__ __forceinline__ void gload16(const char* g, char* l) {
    __builtin_amdgcn_global_load_lds(
        (const __attribute__((address_space(1))) void*)g,
        (__attribute__((address_space(3))) void*)l, 16, 0, 0);
}

// ---------------------------------------------------------------------------
// Transpose + cast: in (K x N) f32  ->  out (N x K) bf16
// ---------------------------------------------------------------------------
__global__ __launch_bounds__(256) void transpose_cast(
    const float* __restrict__ in, unsigned short* __restrict__ out,
    int K, int N)
{
    __shared__ float tile[32][33];
    const int tx = threadIdx.x, ty = threadIdx.y;  // (32, 8)
    const int n0 = blockIdx.x * 32, k0 = blockIdx.y * 32;
    #pragma unroll
    for (int i = 0; i < 32; i += 8)
        tile[ty + i][tx] = in[(long)(k0 + ty + i) * N + n0 + tx];
    __syncthreads();
    #pragma unroll
    for (int i = 0; i < 32; i += 8)
        out[(long)(n0 + ty + i) * K + k0 + tx] = f2bf(tile[tx][ty + i]);
}

// ---------------------------------------------------------------------------
// Elementwise cast f32 -> bf16 (vectorized, grid-stride)
// ---------------------------------------------------------------------------
__global__ __launch_bounds__(256) void cast_f32_bf16(
    const float* __restrict__ in, unsigned short* __restrict__ out, long n)
{
    const long stride = (long)gridDim.x * 256 * 8;
    for (long i = ((long)blockIdx.x * 256 + threadIdx.x) * 8; i < n; i += stride) {
        const f32x4 u0 = *(const f32x4*)&in[i];
        const f32x4 u1 = *(const f32x4*)&in[i + 4];
        us8 w;
        #pragma unroll
        for (int e = 0; e < 4; ++e) { w[e] = f2bf(u0[e]); w[e + 4] = f2bf(u1[e]); }
        *(us8*)&out[i] = w;
    }
}

// ---------------------------------------------------------------------------
// GEMM: C(M,N) = A(M,K) @ BT(N,K)^T + bias(N)       (A, BT bf16; K == 1024)
// 256x256 tile, BK=64, 512 threads (8 waves, 2M x 4N), 128KB dbuf LDS.
// 8-phase counted-lgkm read-ahead K-loop (r7 structure) with BARRIERS ONLY
// at the 4 phases that stage into dying LDS regions or publish a buffer
// (S3, S5, S6, S7).  S0/S1/S2/S4 read data published >= 1 tile ago and
// stage nothing -> their barriers were pure lockstep overhead (r7 ~300cyc
// each).  Counted vmcnt(4) at S5-end; never 0 until the peeled tail.
// ---------------------------------------------------------------------------
#define MFMA16x16(a, b, c) __builtin_amdgcn_mfma_f32_16x16x32_bf16(a, b, c, 0, 0, 0)
#define BAR __builtin_amdgcn_s_barrier()
#define SB  __builtin_amdgcn_sched_barrier(0)
#define P1_ __builtin_amdgcn_s_setprio(1);
#define P0_ __builtin_amdgcn_s_setprio(0);

#define MFMA_H(AA, BB, RO, CO)                                                 \
    _Pragma("unroll") for (int mi_ = 0; mi_ < 4; ++mi_)                        \
        _Pragma("unroll") for (int ni_ = 0; ni_ < 2; ++ni_)                    \
            acc[(RO)+mi_][(CO)+ni_] =                                          \
                MFMA16x16(AA[mi_], BB[ni_], acc[(RO)+mi_][(CO)+ni_]);

#define RD_A(DST, BUFOFF, HIOFF, KS)                                           \
    _Pragma("unroll") for (int mi_ = 0; mi_ < 4; ++mi_)                        \
        DST[mi_] = *(const bf16x8*)(smem + (BUFOFF) + aBase + (HIOFF) + mi_*2048 + (KS));

#define RD_B(DST, BUFOFF, NOFF, KS)                                            \
    _Pragma("unroll") for (int ni_ = 0; ni_ < 2; ++ni_)                        \
        DST[ni_] = *(const bf16x8*)(smem + (BUFOFF) + bBase + ((NOFF)+ni_)*2048 + (KS));

// One K-tile = 8 phases S0..S7.  SG/SR are LITERAL 0/1 (folded).
#define TILE8(T_, BUF, OBUF, SG, SR)                                           \
  do {                                                                         \
    const long gk = (long)((T_) + 2) * 128;                                    \
    /* S0: rd AH0; mfma AL0xBL0 */                                             \
    RD_A(AH0, BUF, 8192, k0)                                                   \
    SB; asm volatile("s_waitcnt lgkmcnt(4)"); SB;                              \
    P1_ MFMA_H(AL0, BL0, 0, 0) P0_                                             \
    /* S1: rd BH0; mfma AH0xBL0 */                                             \
    RD_B(BH0, BUF, 2, k0)                                                      \
    SB; asm volatile("s_waitcnt lgkmcnt(2)"); SB;                              \
    P1_ MFMA_H(AH0, BL0, 4, 0) P0_                                             \
    /* S2: rd AL1; mfma AH0xBH0 */                                             \
    RD_A(AL1, BUF, 0, k1)                                                      \
    SB; asm volatile("s_waitcnt lgkmcnt(4)"); SB;                              \
    P1_ MFMA_H(AH0, BH0, 4, 2) P0_                                             \
    /* S3: rd BL1; stage A j0,j2; mfma AL0xBH0 */                              \
    BAR; RD_B(BL1, BUF, 0, k1)                                                 \
    if (SG) {                                                                  \
        gload16(aStage + (long)(0*64)*Kb + gk, smem + (BUF) + 0*8192 + ldsW);  \
        gload16(aStage + (long)(2*64)*Kb + gk, smem + (BUF) + 2*8192 + ldsW);  \
    }                                                                          \
    SB; asm volatile("s_waitcnt lgkmcnt(2)"); SB;                              \
    P1_ MFMA_H(AL0, BH0, 0, 2) P0_                                             \
    /* S4: rd AH1; mfma AL1xBL1 */                                             \
    RD_A(AH1, BUF, 8192, k1)                                                   \
    SB; asm volatile("s_waitcnt lgkmcnt(4)"); SB;                              \
    P1_ MFMA_H(AL1, BL1, 0, 0) P0_                                             \
    /* S5: rd BH1; stage A j1,j3; mfma AH1xBL1; counted vmcnt */               \
    BAR; RD_B(BH1, BUF, 2, k1)                                                 \
    if (SG) {                                                                  \
        gload16(aStage + (long)(1*64)*Kb + gk, smem + (BUF) + 1*8192 + ldsW);  \
        gload16(aStage + (long)(3*64)*Kb + gk, smem + (BUF) + 3*8192 + ldsW);  \
    }                                                                          \
    SB; asm volatile("s_waitcnt lgkmcnt(2)"); SB;                              \
    P1_ MFMA_H(AH1, BL1, 4, 0) P0_                                             \
    SB;                                                                        \
    if (SG) asm volatile("s_waitcnt vmcnt(4)");                                \
    else    asm volatile("s_waitcnt vmcnt(0)");                                \
    SB;                                                                        \
    /* S6: rd BL0'(OBUF); stage B j0,j1; mfma AH1xBH1 */                       \
    BAR;                                                                       \
    if (SR) { RD_B(BL0, OBUF, 0, k0) }                                         \
    if (SG) {                                                                  \
        gload16(bStage + (long)(0*64)*Kb + gk, smem + (BUF) + 32768 + 0*8192 + ldsW); \
        gload16(bStage + (long)(1*64)*Kb + gk, smem + (BUF) + 32768 + 1*8192 + ldsW); \
    }                                                                          \
    SB;                                                                        \
    if (SR) asm volatile("s_waitcnt lgkmcnt(2)");                              \
    else    asm volatile("s_waitcnt lgkmcnt(0)");                              \
    SB;                                                                        \
    P1_ MFMA_H(AH1, BH1, 4, 2) P0_                                             \
    /* S7: rd AL0'(OBUF); stage B j2,j3; mfma AL1xBH1 */                       \
    BAR;                                                                       \
    if (SR) { RD_A(AL0, OBUF, 0, k0) }                                         \
    if (SG) {                                                                  \
        gload16(bStage + (long)(2*64)*Kb + gk, smem + (BUF) + 32768 + 2*8192 + ldsW); \
        gload16(bStage + (long)(3*64)*Kb + gk, smem + (BUF) + 32768 + 3*8192 + ldsW); \
    }                                                                          \
    SB;                                                                        \
    if (SR) asm volatile("s_waitcnt lgkmcnt(4)");                              \
    else    asm volatile("s_waitcnt lgkmcnt(0)");                              \
    SB;                                                                        \
    P1_ MFMA_H(AL1, BH1, 0, 2) P0_                                             \
  } while (0)

template<bool OUT_BF16>
__global__ __launch_bounds__(512, 2)
void gemm256(const unsigned short* __restrict__ A,   // M x K bf16
             const unsigned short* __restrict__ BT,  // N x K bf16
             const float* __restrict__ bias,
             void* __restrict__ Cp,
             int M, int N, int K)
{
    extern __shared__ char smem[];   // 131072: 2 bufs x (A 32K | B 32K)
    const int tid  = threadIdx.x;
    const int lane = tid & 63;
    const int w    = tid >> 6;      // wave 0..7
    const int wm   = w >> 2;        // 0..1 (M split)
    const int wn   = w & 3;         // 0..3 (N split)

    // XCD-bijective swizzle (launcher guarantees gridDim.x % 8 == 0)
    const int nwg  = gridDim.x;
    const int bid0 = blockIdx.x;
    const int bid  = (bid0 & 7) * (nwg >> 3) + (bid0 >> 3);
    const int nbx  = N >> 8;
    const int bx   = bid % nbx, by = bid / nbx;
    const long rowStart = (long)by * 256;
    const int  colStart = bx * 256;

    const long Kb = (long)K * 2;     // row stride bytes (K == 1024, KT == 16)

    // staging: instr (mat, j) covers tile rows j*64 + w*8 + (lane>>3)
    const int srow = w * 8 + (lane >> 3);
    const int scol = ((lane & 7) ^ (lane >> 3)) << 4;   // inverse-swizzled src col
    const char* aStage = (const char*)A  + (rowStart + srow) * Kb + scol;
    const char* bStage = (const char*)BT + ((long)colStart + srow) * Kb + scol;
    const int ldsW = w * 1024;

    // fragment-read offsets (swizzled)
    const int fr = lane & 15;
    const int kq = lane >> 4;                      // 0..3
    const int sw = (fr & 7) << 4;
    const int k0 = (kq * 16) ^ sw;
    const int k1 = (64 + kq * 16) ^ sw;
    const int aBase = (wm * 128 + fr) * 128;           // bytes, A region
    const int bBase = 32768 + (wn * 64 + fr) * 128;    // bytes, B region

    f32x4 acc[8][4] = {};
    bf16x8 AL0[4], AH0[4], AL1[4], AH1[4], BL0[2], BH0[2], BL1[2], BH1[2];

    // ---- prologue: stage K-tiles 0 (buf0) and 1 (buf1) ----
    #pragma unroll
    for (int tt = 0; tt < 2; ++tt) {
        #pragma unroll
        for (int j = 0; j < 4; ++j)
            gload16(aStage + (long)(j * 64) * Kb + (long)tt * 128,
                    smem + tt * 65536 + j * 8192 + ldsW);
        #pragma unroll
        for (int j = 0; j < 4; ++j)
            gload16(bStage + (long)(j * 64) * Kb + (long)tt * 128,
                    smem + tt * 65536 + 32768 + j * 8192 + ldsW);
    }
    asm volatile("s_waitcnt vmcnt(8)");   // tile 0 landed; tile 1 in flight
    BAR;                                   // publish tile-0 stages
    RD_B(BL0, 0, 0, k0)                    // preload S0 operands (6 reads)
    RD_A(AL0, 0, 0, k0)
    // S0's lgkmcnt(4) (after its 4 AH0 reads) drains these 6.

    #pragma unroll 1
    for (int tp = 0; tp < 7; ++tp) {       // tiles 0..13, full pipeline
        TILE8(2 * tp,     0,     65536, 1, 1);
        TILE8(2 * tp + 1, 65536, 0,     1, 1);
    }
    TILE8(14, 0,     65536, 0, 1);         // no staging; drain vmcnt
    TILE8(15, 65536, 0,     0, 0);         // tail: no next-tile reads

    // ---- epilogue: C/D frag layout col=lane&15, row=(lane>>4)*4+e ----
    float bv[4];
    #pragma unroll
    for (int ni = 0; ni < 4; ++ni)
        bv[ni] = bias[colStart + wn * 64 + ni * 16 + fr];
    #pragma unroll
    for (int mi = 0; mi < 8; ++mi) {
        #pragma unroll
        for (int ni = 0; ni < 4; ++ni) {
            const int col = colStart + wn * 64 + ni * 16 + fr;
            #pragma unroll
            for (int e = 0; e < 4; ++e) {
                const long row = rowStart + wm * 128 + mi * 16 + kq * 4 + e;
                const float val = acc[mi][ni][e] + bv[ni];
                if constexpr (OUT_BF16)
                    ((unsigned short*)Cp)[row * N + col] = f2bf(val);
                else
                    ((float*)Cp)[row * N + col] = val;
            }
        }
    }
}

// ---------------------------------------------------------------------------
// Per-token head-mixing attention (unchanged, verified).
// ---------------------------------------------------------------------------
__global__ __launch_bounds__(256) void attn_kernel(
    const unsigned short* __restrict__ qkv, unsigned short* __restrict__ out)
{
    __shared__ unsigned short qkvs[4][3072];
    __shared__ float ps[4][256];
    __shared__ unsigned short os[4][1024];
    const int tid = threadIdx.x, lane = tid & 63, wave = tid >> 6;
    const long blockTok = (long)blockIdx.x * 4;

    const unsigned short* src = qkv + blockTok * 3072;
    unsigned short* dstBase = &qkvs[0][0];
    #pragma unroll
    for (int i = 0; i < 6; ++i) {
        const int o = (i * 256 + tid) * 8;
        *(us8*)&dstBase[o] = *(const us8*)&src[o];
    }
    __syncthreads();

    const unsigned short* q = &qkvs[wave][0];
    const unsigned short* kk = &qkvs[wave][1024];
    const unsigned short* vv = &qkvs[wave][2048];
    const int h = lane >> 2, g4 = lane & 3;

    float s[4] = {0.f, 0.f, 0.f, 0.f};
    #pragma unroll
    for (int d0 = 0; d0 < 64; d0 += 8) {
        const us8 q8 = *(const us8*)&q[h * 64 + d0];
        float qf[8];
        #pragma unroll
        for (int e = 0; e < 8; ++e) qf[e] = bf2f(q8[e]);
        #pragma unroll
        for (int j = 0; j < 4; ++j) {
            const us8 k8 = *(const us8*)&kk[(g4 * 4 + j) * 64 + d0];
            #pragma unroll
            for (int e = 0; e < 8; ++e) s[j] += qf[e] * bf2f(k8[e]);
        }
    }
    #pragma unroll
    for (int j = 0; j < 4; ++j) s[j] *= 0.125f;

    float mx = fmaxf(fmaxf(s[0], s[1]), fmaxf(s[2], s[3]));
    mx = fmaxf(mx, __shfl_xor(mx, 1, 64));
    mx = fmaxf(mx, __shfl_xor(mx, 2, 64));
    float p[4], sum = 0.f;
    #pragma unroll
    for (int j = 0; j < 4; ++j) { p[j] = expf(s[j] - mx); sum += p[j]; }
    sum += __shfl_xor(sum, 1, 64);
    sum += __shfl_xor(sum, 2, 64);
    const float inv = 1.f / sum;
    #pragma unroll
    for (int j = 0; j < 4; ++j) ps[wave][h * 16 + g4 * 4 + j] = p[j] * inv;
    __syncthreads();

    const int db = lane & 3;
    float o16[16] = {};
    #pragma unroll
    for (int gq = 0; gq < 4; ++gq) {
        const f32x4 pv = *(const f32x4*)&ps[wave][h * 16 + gq * 4];
        #pragma unroll
        for (int j = 0; j < 4; ++j) {
            const float pg = pv[j];
            const int g = gq * 4 + j;
            const us8 v8a = *(const us8*)&vv[g * 64 + db * 16];
            const us8 v8b = *(const us8*)&vv[g * 64 + db * 16 + 8];
            #pragma unroll
            for (int e = 0; e < 8; ++e) {
                o16[e]     += pg * bf2f(v8a[e]);
                o16[8 + e] += pg * bf2f(v8b[e]);
            }
        }
    }
    us8 w0, w1;
    #pragma unroll
    for (int e = 0; e < 8; ++e) { w0[e] = f2bf(o16[e]); w1[e] = f2bf(o16[8 + e]); }
    *(us8*)&os[wave][h * 64 + db * 16] = w0;
    *(us8*)&os[wave][h * 64 + db * 16 + 8] = w1;
    __syncthreads();

    #pragma unroll
    for (int i = 0; i < 2; ++i) {
        const int c = i * 256 + tid;
        const int w2 = c >> 7;
        const int cc = c & 127;
        const long m = blockTok + w2;
        const long n_ = m >> 12;
        const int t = (int)(m & 4095);
        const int hh = cc >> 3, slot = cc & 7;
        const long row = n_ * 4096 + hh * 256 + (t >> 4);
        const long colb = (long)(t & 15) * 128 + slot * 16;
        *(us8*)((char*)out + row * 2048 + colb) = *(const us8*)&os[w2][cc * 8];
    }
}

// ---------------------------------------------------------------------------
extern "C" void kernel_launch(void* const* d_in, const int* in_sizes, int n_in,
                              void* d_out, int out_size, void* d_ws, size_t ws_size,
                              hipStream_t stream) {
    const float* x      = (const float*)d_in[0];  // (16,4096,1024)
    const float* w_qkv  = (const float*)d_in[1];  // (1024,3072)
    const float* b_qkv  = (const float*)d_in[2];  // (3072)
    const float* w_proj = (const float*)d_in[3];  // (1024,1024)
    const float* b_proj = (const float*)d_in[4];  // (1024)

    const long M = 65536;  // 16*4096 tokens
    const size_t QKV_B = (size_t)M * 3072 * 2;    // 402,653,184
    const size_t XB_B  = (size_t)M * 1024 * 2;    // 134,217,728 (x-bf16, then attnout)
    const size_t WQ_B  = 3072 * 1024 * 2;
    const size_t WP_B  = 1024 * 1024 * 2;
    if (ws_size < QKV_B + XB_B + WQ_B + WP_B) return;  // ~545MB

    char* ws = (char*)d_ws;
    unsigned short* qkv    = (unsigned short*)ws;
    unsigned short* xb     = (unsigned short*)(ws + QKV_B);          // also attnout
    unsigned short* wqkvT  = (unsigned short*)(ws + QKV_B + XB_B);
    unsigned short* wprojT = (unsigned short*)(ws + QKV_B + XB_B + WQ_B);

    hipFuncSetAttribute((const void*)gemm256<true>,
                        hipFuncAttributeMaxDynamicSharedMemorySize, 131072);
    hipFuncSetAttribute((const void*)gemm256<false>,
                        hipFuncAttributeMaxDynamicSharedMemorySize, 131072);

    dim3 tb(32, 8);
    transpose_cast<<<dim3(3072 / 32, 1024 / 32), tb, 0, stream>>>(w_qkv, wqkvT, 1024, 3072);
    transpose_cast<<<dim3(1024 / 32, 1024 / 32), tb, 0, stream>>>(w_proj, wprojT, 1024, 1024);
    cast_f32_bf16<<<2048, 256, 0, stream>>>(x, xb, M * 1024);

    // qkv = x @ w_qkv + b_qkv   (bf16 out); grid 12*256=3072 (%8==0)
    gemm256<true><<<dim3((3072 / 256) * (M / 256)), 512, 131072, stream>>>(
        xb, wqkvT, b_qkv, qkv, (int)M, 3072, 1024);

    // per-token attention -> scrambled attnout (bf16), reusing xb
    attn_kernel<<<dim3(M / 4), 256, 0, stream>>>(qkv, xb);

    // out = attnout @ w_proj + b_proj   (f32 out); grid 4*256=1024 (%8==0)
    gemm256<false><<<dim3((1024 / 256) * (M / 256)), 512, 131072, stream>>>(
        xb, wprojT, b_proj, d_out, (int)M, 1024, 1024);
}